// Round 3
// baseline (571.608 us; speedup 1.0000x reference)
//
#include <hip/hip_runtime.h>
#include <hip/hip_bf16.h>

// MOELoraLinear: out = x@W_base^T + b_base + SCALING * router-weighted LoRA.
// LoRA-up folded into main GEMM via K-extension: Xext[8192,4224]=[bf16(x)|hw'|0pad],
// Wext[4096,4224]=[bf16(W_base)|lora_B|0pad]; one bf16 MFMA GEMM K=4224 + bias.
// R5: k_main compute switched 16x16x32 -> 32x32x16 (shape ceiling 2176->2495 TF,
//     half the MFMA instructions). Staging/LDS image/vmcnt skeleton unchanged
//     (verified in R1-R2). k_convx 1024 blocks; k_red unroll 8.

typedef unsigned short u16;
typedef __attribute__((ext_vector_type(8))) short short8;       // 8 bf16 (MFMA A/B frag)
typedef __attribute__((ext_vector_type(8))) unsigned short u16x8;
typedef __attribute__((ext_vector_type(4))) float f32x4;        // 16x16 MFMA C/D frag
typedef __attribute__((ext_vector_type(16))) float f32x16;      // 32x32 MFMA C/D frag

#define AS1(p) ((const __attribute__((address_space(1))) void*)(p))
#define AS3(p) ((__attribute__((address_space(3))) void*)(p))

constexpr int KM   = 4224;   // extended+padded K (66 * 64), row stride of Xext/Wext
constexpr int NOUT = 4096;

__device__ __forceinline__ u16 f2bf(float f) {
    union { float f; unsigned int u; } v; v.f = f;
    unsigned int r = v.u + 0x7fffu + ((v.u >> 16) & 1u);   // RNE
    return (u16)(r >> 16);
}

// ---- fused: x fp32 -> bf16 into Xext[:, :4096]  +  per-block column sums ----
// grid 1024: b = blk>>8, sc = blk&255 -> rows [b*2048 + sc*8, +8)
__global__ __launch_bounds__(256) void k_convx(const float* __restrict__ x,
                                               u16* __restrict__ Xext,
                                               float* __restrict__ colpart) {
    const int t = threadIdx.x;
    const int row0 = (blockIdx.x >> 8) * 2048 + (blockIdx.x & 255) * 8;
    float4 cs[4] = {{0,0,0,0},{0,0,0,0},{0,0,0,0},{0,0,0,0}};   // [g*2+h]
    for (int r = 0; r < 8; ++r) {
        size_t roff = (size_t)(row0 + r) * 4096;
        #pragma unroll
        for (int g = 0; g < 2; ++g) {
            int col = g * 2048 + t * 8;
            const float4* p = (const float4*)(x + roff + col);
            float4 v0 = p[0], v1 = p[1];
            cs[2*g].x += v0.x; cs[2*g].y += v0.y; cs[2*g].z += v0.z; cs[2*g].w += v0.w;
            cs[2*g+1].x += v1.x; cs[2*g+1].y += v1.y; cs[2*g+1].z += v1.z; cs[2*g+1].w += v1.w;
            u16x8 o;
            o[0]=f2bf(v0.x); o[1]=f2bf(v0.y); o[2]=f2bf(v0.z); o[3]=f2bf(v0.w);
            o[4]=f2bf(v1.x); o[5]=f2bf(v1.y); o[6]=f2bf(v1.z); o[7]=f2bf(v1.w);
            *(u16x8*)(Xext + (size_t)(row0 + r) * KM + col) = o;
        }
    }
    float* cp = colpart + (size_t)blockIdx.x * 4096;
    #pragma unroll
    for (int g = 0; g < 2; ++g) {
        *(float4*)(cp + g * 2048 + t * 8)     = cs[2*g];
        *(float4*)(cp + g * 2048 + t * 8 + 4) = cs[2*g+1];
    }
}

// ---- colsum[b][c] = sum_sc colpart[b*256+sc][c]; grid 64 = b*16+chunk ----
__global__ __launch_bounds__(256) void k_red(const float* __restrict__ colpart,
                                             float* __restrict__ colsum) {
    const int b = blockIdx.x >> 4;
    const int col = (blockIdx.x & 15) * 256 + threadIdx.x;
    const float* p = colpart + (size_t)b * 256 * 4096 + col;
    float acc = 0.f;
    #pragma unroll 8
    for (int sc = 0; sc < 256; ++sc) acc += p[(size_t)sc * 4096];
    colsum[b * 4096 + col] = acc;
}

// ---- logits_raw[b,e] = sum_col colsum[b,col] * rW[e,col]  (grid 32 = b*8+e) ----
__global__ __launch_bounds__(256) void k_lgt(const float* __restrict__ colsum,
                                             const float* __restrict__ rW,
                                             float* __restrict__ logits) {
    const int b = blockIdx.x >> 3, e = blockIdx.x & 7;
    const int t = threadIdx.x;
    const float4* cp = (const float4*)(colsum + b * 4096 + t * 16);
    const float4* wp = (const float4*)(rW + e * 4096 + t * 16);
    float acc = 0.f;
    #pragma unroll
    for (int j = 0; j < 4; ++j) {
        float4 c = cp[j], w = wp[j];
        acc += c.x * w.x + c.y * w.y + c.z * w.z + c.w * w.w;
    }
    __shared__ float red[256];
    red[t] = acc;
    __syncthreads();
    for (int off = 128; off > 0; off >>= 1) {
        if (t < off) red[t] += red[t + off];
        __syncthreads();
    }
    if (t == 0) logits[b * 8 + e] = red[0];
}

// ---- W_base fp32 [4096][4096] -> bf16 into Wext[:, :4096] ----
__global__ void k_conv8(const float* __restrict__ src, u16* __restrict__ dst) {
    size_t t = (size_t)blockIdx.x * 256 + threadIdx.x;
    size_t base = t * 8;
    size_t row = base >> 12;
    int col = (int)(base & 4095);
    const float4* s = (const float4*)(src + base);
    float4 v0 = s[0], v1 = s[1];
    u16x8 o;
    o[0]=f2bf(v0.x); o[1]=f2bf(v0.y); o[2]=f2bf(v0.z); o[3]=f2bf(v0.w);
    o[4]=f2bf(v1.x); o[5]=f2bf(v1.y); o[6]=f2bf(v1.z); o[7]=f2bf(v1.w);
    *(u16x8*)(dst + row * KM + col) = o;
}

// ---- lora_B [E,O,R] fp32 -> Wext[o][4096 + e*8 + r]; also zero K-pad [4160,4224) ----
__global__ void k_wlora(const float* __restrict__ lb, u16* __restrict__ Wext) {
    int f = blockIdx.x * 256 + threadIdx.x;
    int e = f >> 15, o = (f >> 3) & 4095, r = f & 7;
    Wext[(size_t)o * KM + 4096 + e * 8 + r] = f2bf(lb[f]);
    // pad zero: f in [0, 262144) == 4096 rows x 64 pad cols
    Wext[(size_t)(f >> 6) * KM + 4160 + (f & 63)] = 0;
}

// ---- lora_A [E,R,D] fp32 -> Abf [64][4096] bf16 ----
__global__ void k_abf(const float* __restrict__ la, u16* __restrict__ Abf) {
    int f = blockIdx.x * 256 + threadIdx.x;
    Abf[f] = f2bf(la[f]);
}

// ---- h-GEMM: Xext[:, 4096+er] = f2bf( (Xbf @ Abf^T)[m,er] * SCALING*softmax(...)[b(m),e] )
// grid 256 blocks x 256 thr (4 waves). M-tile 32. Each wave owns K-chunk of 1024,
// private double-buffered LDS, no in-loop barriers; cross-wave LDS reduce at end.
// Also zero-fills the K-pad columns [4160,4224) of its 32 rows.
__global__ __launch_bounds__(256) void k_hgemm(const u16* __restrict__ Xb,
                                               const u16* __restrict__ Ab,
                                               const float* __restrict__ logits,
                                               const float* __restrict__ rb,
                                               u16* __restrict__ Hout) {
    __shared__ u16 As[8 * 1024];     // [wave*2+buf][32*32]
    __shared__ u16 Bs[8 * 2048];     // [wave*2+buf][64*32]
    __shared__ float Red[4 * 2048];  // [wave][32*64]
    __shared__ float wscL[8];
    const int tid = threadIdx.x, lane = tid & 63, w = tid >> 6;
    const int m0 = blockIdx.x * 32;
    const int b = blockIdx.x >> 6;      // batch (2048 rows = 64 blocks per batch)

    if (tid < 8) {
        float l[8], mx = -1e30f;
        #pragma unroll
        for (int j = 0; j < 8; ++j) {
            l[j] = logits[b * 8 + j] * (1.0f / 2048.0f) + rb[j];
            mx = fmaxf(mx, l[j]);
        }
        float s = 0.f;
        #pragma unroll
        for (int j = 0; j < 8; ++j) s += expf(l[j] - mx);
        wscL[tid] = 2.0f * expf(l[tid] - mx) / s;   // SCALING = 2.0
    }
    // drain the logits/rb loads so they don't pollute vmcnt bookkeeping below
    asm volatile("s_waitcnt vmcnt(0)" ::: "memory");

    f32x4 acc[2][4] = {};
    const int kbase = w * 1024;

    auto issue = [&](int it, int buf) {
        const int kt = kbase + it * 32;
        u16* Aw = As + (w * 2 + buf) * 1024;
        u16* Bw = Bs + (w * 2 + buf) * 2048;
        #pragma unroll
        for (int i = 0; i < 2; ++i) {
            int f = lane + i * 64;
            __builtin_amdgcn_global_load_lds(
                AS1(Xb + (size_t)(m0 + (f >> 2)) * KM + kt + (f & 3) * 8),
                AS3(Aw + f * 8), 16, 0, 0);
        }
        #pragma unroll
        for (int i = 0; i < 4; ++i) {
            int f = lane + i * 64;
            __builtin_amdgcn_global_load_lds(
                AS1(Ab + (size_t)(f >> 2) * 4096 + kt + (f & 3) * 8),
                AS3(Bw + f * 8), 16, 0, 0);
        }
    };

    issue(0, 0);
    for (int it = 0; it < 32; ++it) {
        const int buf = it & 1;
        if (it + 1 < 32) {
            issue(it + 1, buf ^ 1);
            asm volatile("s_waitcnt vmcnt(6)" ::: "memory");   // drain the 6 older (this iter's) DMAs
        } else {
            asm volatile("s_waitcnt vmcnt(0)" ::: "memory");
        }
        const u16* Aw = As + (w * 2 + buf) * 1024;
        const u16* Bw = Bs + (w * 2 + buf) * 2048;
        short8 af[2], bfr[4];
        #pragma unroll
        for (int mi = 0; mi < 2; ++mi)
            af[mi] = *(const short8*)(Aw + (mi * 16 + (lane & 15)) * 32 + (lane >> 4) * 8);
        #pragma unroll
        for (int nj = 0; nj < 4; ++nj)
            bfr[nj] = *(const short8*)(Bw + (nj * 16 + (lane & 15)) * 32 + (lane >> 4) * 8);
        #pragma unroll
        for (int mi = 0; mi < 2; ++mi)
            #pragma unroll
            for (int nj = 0; nj < 4; ++nj)
                acc[mi][nj] = __builtin_amdgcn_mfma_f32_16x16x32_bf16(af[mi], bfr[nj], acc[mi][nj], 0, 0, 0);
        asm volatile("" ::: "memory");
    }

    const int quad = lane >> 4, lcol = lane & 15;
    #pragma unroll
    for (int mi = 0; mi < 2; ++mi)
        #pragma unroll
        for (int nj = 0; nj < 4; ++nj)
            #pragma unroll
            for (int r = 0; r < 4; ++r)
                Red[w * 2048 + (mi * 16 + quad * 4 + r) * 64 + nj * 16 + lcol] = acc[mi][nj][r];
    __syncthreads();

    const int o = tid * 8, row = o >> 6, col = o & 63;
    float s0=0,s1=0,s2=0,s3=0,s4=0,s5=0,s6=0,s7=0;
    #pragma unroll
    for (int ww = 0; ww < 4; ++ww) {
        const float4* p = (const float4*)(Red + ww * 2048 + o);
        float4 v0 = p[0], v1 = p[1];
        s0+=v0.x; s1+=v0.y; s2+=v0.z; s3+=v0.w;
        s4+=v1.x; s5+=v1.y; s6+=v1.z; s7+=v1.w;
    }
    const float wgt = wscL[col >> 3];
    u16x8 out;
    out[0]=f2bf(s0*wgt); out[1]=f2bf(s1*wgt); out[2]=f2bf(s2*wgt); out[3]=f2bf(s3*wgt);
    out[4]=f2bf(s4*wgt); out[5]=f2bf(s5*wgt); out[6]=f2bf(s6*wgt); out[7]=f2bf(s7*wgt);
    *(u16x8*)(Hout + (size_t)(m0 + row) * KM + 4096 + col) = out;
    // zero K-pad: 32 rows x 64 cols per block
    u16x8 zz = {0,0,0,0,0,0,0,0};
    *(u16x8*)(Hout + (size_t)(m0 + (tid >> 3)) * KM + 4160 + (tid & 7) * 8) = zz;
}

// ================= main GEMM: 256x256 tile, BK=64, 8-phase, 32x32x16 MFMA =================
// C[8192,4096] = Xext @ Wext^T + bias. K = 4224 = 66 tiles of 64, 2 tiles/iteration.
// LDS (bytes): buf b in {0,1}: A @ b*65536 (q0:0-8K q1:8-16K q2:16-24K q3:24-32K);
//              B @ b*65536+32768 (h0: +0-16K, h1: +16-32K).
// Swizzle: logical (row, colbyte) stored at colbyte ^ ((row&7)<<4) within each 128B row.
// Wave tile 128x64 as 4x2 of 32x32 frags; phase pq computes mi=pq (2 nj x 4 ks = 8 MFMA).
// A/B operand layout (32x32x16): lane holds row/col = lane&31, k = (lane>>5)*8 + j.
// Staging & waits identical to R4 (verified): P1:A(t+1){q0,q2} P2:A(t+1){q1,q3}
// P3:B(t+2)h0 P4:B(t+2)h1 P5..P8 same for t+2/t+3; vmcnt 8/6/8/6; tail 8/2/0/skip.

#define LDB_(bufB) do { \
    const char* bp_ = ldsc + bBaseB + (bufB); \
    _Pragma("unroll") \
    for (int nj_ = 0; nj_ < 2; ++nj_) \
        _Pragma("unroll") \
        for (int ks_ = 0; ks_ < 4; ++ks_) \
            bf[nj_][ks_] = *(const short8*)(bp_ + nj_ * 4096 + ardk[ks_]); \
} while (0)

#define LDA_(bufB, pq) do { \
    const char* ap_ = ldsc + aBaseB + (bufB) + (pq) * 4096; \
    _Pragma("unroll") \
    for (int ks_ = 0; ks_ < 4; ++ks_) \
        af[ks_] = *(const short8*)(ap_ + ardk[ks_]); \
} while (0)

// ks outer, nj inner: dependent MFMAs separated by 1 independent issue
#define MFMA_(pq) do { \
    __builtin_amdgcn_s_barrier(); \
    asm volatile("s_waitcnt lgkmcnt(0)" ::: "memory"); \
    __builtin_amdgcn_sched_barrier(0); \
    __builtin_amdgcn_s_setprio(1); \
    _Pragma("unroll") \
    for (int ks_ = 0; ks_ < 4; ++ks_) \
        _Pragma("unroll") \
        for (int nj_ = 0; nj_ < 2; ++nj_) \
            acc[(pq)][nj_] = __builtin_amdgcn_mfma_f32_32x32x16_bf16(af[ks_], bf[nj_][ks_], acc[(pq)][nj_], 0, 0, 0); \
    __builtin_amdgcn_s_setprio(0); \
    __builtin_amdgcn_sched_barrier(0); \
} while (0)

#define ENDPH_() __builtin_amdgcn_s_barrier()
#define VM_(n)   asm volatile("s_waitcnt vmcnt(" #n ")" ::: "memory")

__global__ __launch_bounds__(512, 2) void k_main(const u16* __restrict__ A, const u16* __restrict__ B,
                                                 const float* __restrict__ bias, float* __restrict__ C) {
    __shared__ __align__(16) u16 lds[65536];   // 128 KiB
    const char* ldsc = (const char*)lds;
    const int tid = threadIdx.x;
    const int lane = tid & 63;
    const int w = tid >> 6;
    const int wm = w >> 2;        // 0..1  (M half)
    const int wn = w & 3;         // 0..3  (N quarter)

    // bijective XCD swizzle: 512 blocks, 64/XCD; tiles 32(M) x 16(N), N fast (A-panel L2 reuse)
    const int bid = blockIdx.x;
    const int swz = (bid & 7) * 64 + (bid >> 3);
    const int m0 = (swz >> 4) * 256;
    const int n0 = (swz & 15) * 256;

    // 32x32 operand read offsets (swizzled; XOR depends only on lane)
    const int l31 = lane & 31, hi32 = lane >> 5;
    const int csw = (lane & 7) << 4;
    const int ardk[4] = {
        l31 * 128 + ((0 * 32 + hi32 * 16) ^ csw),
        l31 * 128 + ((1 * 32 + hi32 * 16) ^ csw),
        l31 * 128 + ((2 * 32 + hi32 * 16) ^ csw),
        l31 * 128 + ((3 * 32 + hi32 * 16) ^ csw),
    };
    const int aBaseB = wm * 16384;                                      // buf0 A (wm half)
    const int bBaseB = 32768 + (wn >> 1) * 16384 + (wn & 1) * 8192;     // buf0 B (wn quarter)

    // staging: thread tid writes linear LDS bytes [tid*16 + region]; logical row
    // = region_row0 + (tid>>3), source col pre-inverse-swizzled by ((row&7)<<4).
    const int srow = tid >> 3;                                   // 0..63
    const int scol = ((tid & 7) ^ ((tid >> 3) & 7)) * 8;         // elements, [0,64)
    const int so0 = srow * KM + scol;
    const int so1 = (64 + srow) * KM + scol;
    const u16* Am0 = A + (size_t)m0 * KM;
    const u16* Am1 = A + (size_t)(m0 + 128) * KM;
    const u16* Bm0 = B + (size_t)n0 * KM;
    const u16* Bm1 = B + (size_t)(n0 + 128) * KM;
    u16* ldst = lds + tid * 8;                                   // element base for DMA dest

    // B half-tile stage (rows r0..r0+127): 2 loads
    auto stageB = [&](const u16* src, int t, int regionEl) {
        __builtin_amdgcn_global_load_lds(AS1(src + so0 + t * 64), AS3(ldst + regionEl), 16, 0, 0);
        __builtin_amdgcn_global_load_lds(AS1(src + so1 + t * 64), AS3(ldst + regionEl + 4096), 16, 0, 0);
    };
    // A quarter-pair stage: which=0 -> {q0: rows 0-63, q2: rows 128-191};
    //                       which=1 -> {q1: rows 64-127, q3: rows 192-255}. 2 loads.
    auto stageA = [&](int t, int bufEl, int which) {
        const size_t ro = (size_t)(which * 64) * KM;
        __builtin_amdgcn_global_load_lds(AS1(Am0 + ro + so0 + t * 64),
                                         AS3(ldst + bufEl + which * 4096), 16, 0, 0);
        __builtin_amdgcn_global_load_lds(AS1(Am1 + ro + so0 + t * 64),
                                         AS3(ldst + bufEl + 8192 + which * 4096), 16, 0, 0);
    };

    f32x16 acc[4][2] = {};

    // prologue: B(0)h0, B(0)h1, A(0)w0, A(0)w1, B(1)h0, B(1)h1  (12 loads)
    stageB(Bm0, 0, 16384);
    stageB(Bm1, 0, 24576);
    stageA(0, 0, 0);
    stageA(0, 0, 1);
    stageB(Bm0, 1, 32768 + 16384);
    stageB(Bm1, 1, 32768 + 24576);
    VM_(6);                      // B(0) full + A(0){q0,q2} complete
    __builtin_amdgcn_s_barrier();

    #pragma unroll 1
    for (int i = 0; i < 33; ++i) {
        const int t = i * 2;
        const bool nl = (i < 32);
        short8 af[4];
        short8 bf[2][4];
        // -------- K-tile t (buf0) --------
        LDB_(0); LDA_(0, 0);
        stageA(t + 1, 32768, 0);
        MFMA_(0); ENDPH_();
        LDA_(0, 1);
        stageA(t + 1, 32768, 1);
        MFMA_(1); VM_(8); ENDPH_();                  // A(t){q1,q3} complete
        LDA_(0, 2);
        if (nl) stageB(Bm0, t + 2, 16384);
        MFMA_(2); ENDPH_();
        LDA_(0, 3);
        if (nl) stageB(Bm1, t + 2, 24576);
        MFMA_(3);
        if (nl) { VM_(6); } else { VM_(2); }         // B(t+1) + A(t+1){q0,q2}
        ENDPH_();
        // -------- K-tile t+1 (buf1) --------
        LDB_(65536); LDA_(65536, 0);
        if (nl) stageA(t + 2, 0, 0);
        MFMA_(0); ENDPH_();
        LDA_(65536, 1);
        if (nl) stageA(t + 2, 0, 1);
        MFMA_(1);
        if (nl) { VM_(8); } else { VM_(0); }         // A(t+1){q1,q3}
        ENDPH_();
        LDA_(65536, 2);
        if (nl) stageB(Bm0, t + 3, 32768 + 16384);
        MFMA_(2); ENDPH_();
        LDA_(65536, 3);
        if (nl) stageB(Bm1, t + 3, 32768 + 24576);
        MFMA_(3);
        if (nl) { VM_(6); }                          // B(t+2) + A(t+2){q0,q2}
        ENDPH_();
    }

    // epilogue: 32x32 C/D layout: col=lane&31, row=(reg&3)+8*(reg>>2)+4*(lane>>5)
    const int colb = n0 + wn * 64 + l31;
    const int rowb = m0 + wm * 128 + hi32 * 4;
    #pragma unroll
    for (int nj = 0; nj < 2; ++nj) {
        const int col = colb + nj * 32;
        const float bv = bias[col];
        #pragma unroll
        for (int mi = 0; mi < 4; ++mi) {
            #pragma unroll
            for (int g = 0; g < 4; ++g) {
                float* Cp = C + (size_t)(rowb + mi * 32 + g * 8) * NOUT + col;
                #pragma unroll
                for (int j = 0; j < 4; ++j)
                    Cp[(size_t)j * NOUT] = acc[mi][nj][g * 4 + j] + bv;
            }
        }
    }
}

extern "C" void kernel_launch(void* const* d_in, const int* in_sizes, int n_in,
                              void* d_out, int out_size, void* d_ws, size_t ws_size,
                              hipStream_t stream) {
    const float* x  = (const float*)d_in[0];   // [4,2048,4096]
    const float* Wb = (const float*)d_in[1];   // [4096,4096]
    const float* bb = (const float*)d_in[2];   // [4096]
    const float* lA = (const float*)d_in[3];   // [8,8,4096]
    const float* lB = (const float*)d_in[4];   // [8,4096,8]
    const float* rW = (const float*)d_in[5];   // [8,4096]
    const float* rb = (const float*)d_in[6];   // [8]
    float* out = (float*)d_out;                // [4,2048,4096] fp32

    char* ws = (char*)d_ws;
    float* logits = (float*)ws;                            // 32 fp32
    u16* Abf      = (u16*)(ws + 256);                      // 64*4096 bf16 = 512 KiB
    u16* Xext     = (u16*)(ws + 524800);                   // 8192*4224 bf16 = 69.2 MB
    u16* Wext     = (u16*)(ws + 524800 + 69206016ULL);     // 4096*4224 bf16 = 34.6 MB
    // colpart [1024][4096] fp32 = 16 MB overlaid on Wext[0..16MB); colsum [4][4096]
    // fp32 = 64 KiB overlaid at Wext+20MB. Both fully consumed (k_red/k_lgt) BEFORE
    // k_conv8/k_wlora write Wext (stream-ordered).
    float* colpart = (float*)Wext;
    float* colsum  = (float*)((char*)Wext + (20u << 20));

    k_abf   <<<1024, 256, 0, stream>>>(lA, Abf);             // lora_A -> bf16
    k_convx <<<1024, 256, 0, stream>>>(x, Xext, colpart);    // x -> bf16 + column sums
    k_red   <<<64,   256, 0, stream>>>(colpart, colsum);     // colpart -> per-batch colsum
    k_lgt   <<<32,   256, 0, stream>>>(colsum, rW, logits);  // raw router logits
    k_hgemm <<<256,  256, 0, stream>>>(Xext, Abf, logits, rb, Xext); // hw' -> Xext[:,4096:4160] + pad0
    k_conv8 <<<8192, 256, 0, stream>>>(Wb, Wext);            // W_base -> Wext[:, :4096]
    k_wlora <<<1024, 256, 0, stream>>>(lB, Wext);            // lora_B -> Wext[:, 4096:4160] + pad0
    k_main  <<<512,  512, 0, stream>>>(Xext, Wext, bb, out); // 256^2 8-phase GEMM + bias
}

// Round 4
// 565.056 us; speedup vs baseline: 1.0116x; 1.0116x over previous
//
#include <hip/hip_runtime.h>
#include <hip/hip_bf16.h>

// MOELoraLinear: out = x@W_base^T + b_base + SCALING * router-weighted LoRA.
// LoRA-up folded into main GEMM via K-extension: Xext[8192,4224]=[bf16(x)|hw'|0pad],
// Wext[4096,4224]=[bf16(W_base)|lora_B|0pad]; one bf16 MFMA GEMM K=4224 + bias.
// R6: k_main reverted to the verified R2 16x16x32 schedule (264us, 0 bank conflicts;
//     the 32x32 experiment regressed with 2.6e7 conflicts). Launch graph 8 -> 5:
//     k_prep1 = convx||abf, k_prep2 = hgemm||conv8||wlora (hazard-ordered after k_lgt).

typedef unsigned short u16;
typedef __attribute__((ext_vector_type(8))) short short8;       // 8 bf16 (MFMA A/B frag)
typedef __attribute__((ext_vector_type(8))) unsigned short u16x8;
typedef __attribute__((ext_vector_type(4))) float f32x4;        // MFMA C/D frag

#define AS1(p) ((const __attribute__((address_space(1))) void*)(p))
#define AS3(p) ((__attribute__((address_space(3))) void*)(p))

constexpr int KM   = 4224;   // extended+padded K (66 * 64), row stride of Xext/Wext
constexpr int NOUT = 4096;

__device__ __forceinline__ u16 f2bf(float f) {
    union { float f; unsigned int u; } v; v.f = f;
    unsigned int r = v.u + 0x7fffu + ((v.u >> 16) & 1u);   // RNE
    return (u16)(r >> 16);
}

// ================= prep1: x->bf16 + colpart  ||  lora_A->bf16 =================
// blocks [0,1024): convx b = blk>>8, sc = blk&255 -> rows [b*2048 + sc*8, +8)
// blocks [1024,2048): abf
__global__ __launch_bounds__(256) void k_prep1(const float* __restrict__ x,
                                               u16* __restrict__ Xext,
                                               float* __restrict__ colpart,
                                               const float* __restrict__ la,
                                               u16* __restrict__ Abf) {
    const int t = threadIdx.x;
    if (blockIdx.x < 1024) {
        const int row0 = (blockIdx.x >> 8) * 2048 + (blockIdx.x & 255) * 8;
        float4 cs[4] = {{0,0,0,0},{0,0,0,0},{0,0,0,0},{0,0,0,0}};   // [g*2+h]
        for (int r = 0; r < 8; ++r) {
            size_t roff = (size_t)(row0 + r) * 4096;
            #pragma unroll
            for (int g = 0; g < 2; ++g) {
                int col = g * 2048 + t * 8;
                const float4* p = (const float4*)(x + roff + col);
                float4 v0 = p[0], v1 = p[1];
                cs[2*g].x += v0.x; cs[2*g].y += v0.y; cs[2*g].z += v0.z; cs[2*g].w += v0.w;
                cs[2*g+1].x += v1.x; cs[2*g+1].y += v1.y; cs[2*g+1].z += v1.z; cs[2*g+1].w += v1.w;
                u16x8 o;
                o[0]=f2bf(v0.x); o[1]=f2bf(v0.y); o[2]=f2bf(v0.z); o[3]=f2bf(v0.w);
                o[4]=f2bf(v1.x); o[5]=f2bf(v1.y); o[6]=f2bf(v1.z); o[7]=f2bf(v1.w);
                *(u16x8*)(Xext + (size_t)(row0 + r) * KM + col) = o;
            }
        }
        float* cp = colpart + (size_t)blockIdx.x * 4096;
        #pragma unroll
        for (int g = 0; g < 2; ++g) {
            *(float4*)(cp + g * 2048 + t * 8)     = cs[2*g];
            *(float4*)(cp + g * 2048 + t * 8 + 4) = cs[2*g+1];
        }
    } else {
        int f = (blockIdx.x - 1024) * 256 + t;
        Abf[f] = f2bf(la[f]);
    }
}

// ---- colsum[b][c] = sum_sc colpart[b*256+sc][c]; grid 64 = b*16+chunk ----
__global__ __launch_bounds__(256) void k_red(const float* __restrict__ colpart,
                                             float* __restrict__ colsum) {
    const int b = blockIdx.x >> 4;
    const int col = (blockIdx.x & 15) * 256 + threadIdx.x;
    const float* p = colpart + (size_t)b * 256 * 4096 + col;
    float acc = 0.f;
    #pragma unroll 8
    for (int sc = 0; sc < 256; ++sc) acc += p[(size_t)sc * 4096];
    colsum[b * 4096 + col] = acc;
}

// ---- logits_raw[b,e] = sum_col colsum[b,col] * rW[e,col]  (grid 32 = b*8+e) ----
__global__ __launch_bounds__(256) void k_lgt(const float* __restrict__ colsum,
                                             const float* __restrict__ rW,
                                             float* __restrict__ logits) {
    const int b = blockIdx.x >> 3, e = blockIdx.x & 7;
    const int t = threadIdx.x;
    const float4* cp = (const float4*)(colsum + b * 4096 + t * 16);
    const float4* wp = (const float4*)(rW + e * 4096 + t * 16);
    float acc = 0.f;
    #pragma unroll
    for (int j = 0; j < 4; ++j) {
        float4 c = cp[j], w = wp[j];
        acc += c.x * w.x + c.y * w.y + c.z * w.z + c.w * w.w;
    }
    __shared__ float red[256];
    red[t] = acc;
    __syncthreads();
    for (int off = 128; off > 0; off >>= 1) {
        if (t < off) red[t] += red[t + off];
        __syncthreads();
    }
    if (t == 0) logits[b * 8 + e] = red[0];
}

// ================= prep2: hgemm || conv8 || wlora =================
// blocks [0,256): h-GEMM  Xext[:, 4096+er] = f2bf((Xbf@Abf^T)*wsc)
// blocks [256,8448): W_base fp32 -> bf16 into Wext[:, :4096]
// blocks [8448,9472): lora_B -> Wext[:, 4096:4160] + zero K-pad
__global__ __launch_bounds__(256) void k_prep2(const u16* __restrict__ Xb,
                                               const u16* __restrict__ Ab,
                                               const float* __restrict__ logits,
                                               const float* __restrict__ rb,
                                               u16* __restrict__ Hout,
                                               const float* __restrict__ Wb,
                                               u16* __restrict__ Wext,
                                               const float* __restrict__ lb) {
    const int tid = threadIdx.x;
    if (blockIdx.x < 256) {
        // ---- h-GEMM (verified R2 body): 4 waves, wave-private K-chunk 1024, dbuf LDS ----
        __shared__ u16 As[8 * 1024];     // [wave*2+buf][32*32]
        __shared__ u16 Bs[8 * 2048];     // [wave*2+buf][64*32]
        __shared__ float Red[4 * 2048];  // [wave][32*64]
        __shared__ float wscL[8];
        const int lane = tid & 63, w = tid >> 6;
        const int m0 = blockIdx.x * 32;
        const int b = blockIdx.x >> 6;      // batch (2048 rows = 64 blocks per batch)

        if (tid < 8) {
            float l[8], mx = -1e30f;
            #pragma unroll
            for (int j = 0; j < 8; ++j) {
                l[j] = logits[b * 8 + j] * (1.0f / 2048.0f) + rb[j];
                mx = fmaxf(mx, l[j]);
            }
            float s = 0.f;
            #pragma unroll
            for (int j = 0; j < 8; ++j) s += expf(l[j] - mx);
            wscL[tid] = 2.0f * expf(l[tid] - mx) / s;   // SCALING = 2.0
        }
        asm volatile("s_waitcnt vmcnt(0)" ::: "memory");

        f32x4 acc[2][4] = {};
        const int kbase = w * 1024;

        auto issue = [&](int it, int buf) {
            const int kt = kbase + it * 32;
            u16* Aw = As + (w * 2 + buf) * 1024;
            u16* Bw = Bs + (w * 2 + buf) * 2048;
            #pragma unroll
            for (int i = 0; i < 2; ++i) {
                int f = lane + i * 64;
                __builtin_amdgcn_global_load_lds(
                    AS1(Xb + (size_t)(m0 + (f >> 2)) * KM + kt + (f & 3) * 8),
                    AS3(Aw + f * 8), 16, 0, 0);
            }
            #pragma unroll
            for (int i = 0; i < 4; ++i) {
                int f = lane + i * 64;
                __builtin_amdgcn_global_load_lds(
                    AS1(Ab + (size_t)(f >> 2) * 4096 + kt + (f & 3) * 8),
                    AS3(Bw + f * 8), 16, 0, 0);
            }
        };

        issue(0, 0);
        for (int it = 0; it < 32; ++it) {
            const int buf = it & 1;
            if (it + 1 < 32) {
                issue(it + 1, buf ^ 1);
                asm volatile("s_waitcnt vmcnt(6)" ::: "memory");
            } else {
                asm volatile("s_waitcnt vmcnt(0)" ::: "memory");
            }
            const u16* Aw = As + (w * 2 + buf) * 1024;
            const u16* Bw = Bs + (w * 2 + buf) * 2048;
            short8 af[2], bfr[4];
            #pragma unroll
            for (int mi = 0; mi < 2; ++mi)
                af[mi] = *(const short8*)(Aw + (mi * 16 + (lane & 15)) * 32 + (lane >> 4) * 8);
            #pragma unroll
            for (int nj = 0; nj < 4; ++nj)
                bfr[nj] = *(const short8*)(Bw + (nj * 16 + (lane & 15)) * 32 + (lane >> 4) * 8);
            #pragma unroll
            for (int mi = 0; mi < 2; ++mi)
                #pragma unroll
                for (int nj = 0; nj < 4; ++nj)
                    acc[mi][nj] = __builtin_amdgcn_mfma_f32_16x16x32_bf16(af[mi], bfr[nj], acc[mi][nj], 0, 0, 0);
            asm volatile("" ::: "memory");
        }

        const int quad = lane >> 4, lcol = lane & 15;
        #pragma unroll
        for (int mi = 0; mi < 2; ++mi)
            #pragma unroll
            for (int nj = 0; nj < 4; ++nj)
                #pragma unroll
                for (int r = 0; r < 4; ++r)
                    Red[w * 2048 + (mi * 16 + quad * 4 + r) * 64 + nj * 16 + lcol] = acc[mi][nj][r];
        __syncthreads();

        const int o = tid * 8, row = o >> 6, col = o & 63;
        float s0=0,s1=0,s2=0,s3=0,s4=0,s5=0,s6=0,s7=0;
        #pragma unroll
        for (int ww = 0; ww < 4; ++ww) {
            const float4* p = (const float4*)(Red + ww * 2048 + o);
            float4 v0 = p[0], v1 = p[1];
            s0+=v0.x; s1+=v0.y; s2+=v0.z; s3+=v0.w;
            s4+=v1.x; s5+=v1.y; s6+=v1.z; s7+=v1.w;
        }
        const float wgt = wscL[col >> 3];
        u16x8 out;
        out[0]=f2bf(s0*wgt); out[1]=f2bf(s1*wgt); out[2]=f2bf(s2*wgt); out[3]=f2bf(s3*wgt);
        out[4]=f2bf(s4*wgt); out[5]=f2bf(s5*wgt); out[6]=f2bf(s6*wgt); out[7]=f2bf(s7*wgt);
        *(u16x8*)(Hout + (size_t)(m0 + row) * KM + 4096 + col) = out;
        u16x8 zz = {0,0,0,0,0,0,0,0};
        *(u16x8*)(Hout + (size_t)(m0 + (tid >> 3)) * KM + 4160 + (tid & 7) * 8) = zz;
    } else if (blockIdx.x < 8448) {
        // ---- conv8: W_base -> Wext[:, :4096] ----
        size_t t8 = (size_t)(blockIdx.x - 256) * 256 + tid;
        size_t base = t8 * 8;
        size_t row = base >> 12;
        int col = (int)(base & 4095);
        const float4* s = (const float4*)(Wb + base);
        float4 v0 = s[0], v1 = s[1];
        u16x8 o;
        o[0]=f2bf(v0.x); o[1]=f2bf(v0.y); o[2]=f2bf(v0.z); o[3]=f2bf(v0.w);
        o[4]=f2bf(v1.x); o[5]=f2bf(v1.y); o[6]=f2bf(v1.z); o[7]=f2bf(v1.w);
        *(u16x8*)(Wext + row * KM + col) = o;
    } else {
        // ---- wlora: lora_B -> Wext[:, 4096:4160]; zero K-pad [4160,4224) ----
        int f = (blockIdx.x - 8448) * 256 + tid;
        int e = f >> 15, o = (f >> 3) & 4095, r = f & 7;
        Wext[(size_t)o * KM + 4096 + e * 8 + r] = f2bf(lb[f]);
        Wext[(size_t)(f >> 6) * KM + 4160 + (f & 63)] = 0;
    }
}

// ================= main GEMM: 256x256 tile, BK=64, 8-phase counted-vmcnt =================
// C[8192,4096] = Xext @ Wext^T + bias. K = 4224 = 66 tiles of 64, 2 tiles/iteration.
// LDS (bytes): buf b in {0,1}: A @ b*65536 (q0:0-8K q1:8-16K q2:16-24K q3:24-32K);
//              B @ b*65536+32768 (h0: +0-16K, h1: +16-32K).
// Swizzle: logical (row, colbyte) stored at colbyte ^ ((row&7)<<4) within each 128B row.
// Staging (iter computes tiles t buf0, t+1 buf1), 2 loads per thread per phase:
//   P1:A(t+1){q0,q2}  P2:A(t+1){q1,q3}  P3:B(t+2)h0  P4:B(t+2)h1
//   P5:A(t+2){q0,q2}  P6:A(t+2){q1,q3}  P7:B(t+3)h0  P8:B(t+3)h1
// Waits: end-P2 vmcnt(8), end-P4 vmcnt(6), end-P6 vmcnt(8), end-P8 vmcnt(6).
// Tail (i=32): stages only P1/P2; waits become 8 / 2 / 0 / skip.  [R2-verified: 264us]

#define LDB_(bufB) do { \
    const char* bp_ = ldsc + bBaseB + (bufB); \
    _Pragma("unroll") \
    for (int nj_ = 0; nj_ < 4; ++nj_) { \
        bf[nj_][0] = *(const short8*)(bp_ + nj_ * 2048 + rdk0); \
        bf[nj_][1] = *(const short8*)(bp_ + nj_ * 2048 + rdk1); \
    } \
} while (0)

#define LDA_(bufB, pq) do { \
    const char* ap_ = ldsc + aBaseB + (bufB) + (pq) * 4096; \
    af[0][0] = *(const short8*)(ap_ + rdk0); \
    af[0][1] = *(const short8*)(ap_ + rdk1); \
    af[1][0] = *(const short8*)(ap_ + 2048 + rdk0); \
    af[1][1] = *(const short8*)(ap_ + 2048 + rdk1); \
} while (0)

// k0 sweep then k1 sweep: 8 independent MFMAs between dependent pairs
#define MFMA_(pq) do { \
    __builtin_amdgcn_s_barrier(); \
    asm volatile("s_waitcnt lgkmcnt(0)" ::: "memory"); \
    __builtin_amdgcn_sched_barrier(0); \
    __builtin_amdgcn_s_setprio(1); \
    _Pragma("unroll") \
    for (int k_ = 0; k_ < 2; ++k_) \
        _Pragma("unroll") \
        for (int q_ = 0; q_ < 2; ++q_) \
            _Pragma("unroll") \
            for (int nj_ = 0; nj_ < 4; ++nj_) \
                acc[(pq)*2+q_][nj_] = __builtin_amdgcn_mfma_f32_16x16x32_bf16(af[q_][k_], bf[nj_][k_], acc[(pq)*2+q_][nj_], 0, 0, 0); \
    __builtin_amdgcn_s_setprio(0); \
    __builtin_amdgcn_sched_barrier(0); \
} while (0)

#define ENDPH_() __builtin_amdgcn_s_barrier()
#define VM_(n)   asm volatile("s_waitcnt vmcnt(" #n ")" ::: "memory")

__global__ __launch_bounds__(512, 2) void k_main(const u16* __restrict__ A, const u16* __restrict__ B,
                                                 const float* __restrict__ bias, float* __restrict__ C) {
    __shared__ __align__(16) u16 lds[65536];   // 128 KiB
    const char* ldsc = (const char*)lds;
    const int tid = threadIdx.x;
    const int lane = tid & 63;
    const int w = tid >> 6;
    const int wm = w >> 2;        // 0..1  (M half)
    const int wn = w & 3;         // 0..3  (N quarter)
    const int lr = lane & 15, hi = lane >> 4;

    // bijective XCD swizzle: 512 blocks, 64/XCD; tiles 32(M) x 16(N), N fast (A-panel L2 reuse)
    const int bid = blockIdx.x;
    const int swz = (bid & 7) * 64 + (bid >> 3);
    const int m0 = (swz >> 4) * 256;
    const int n0 = (swz & 15) * 256;

    // ds_read byte offsets within a half-tile region (swizzled; XOR depends only on lane)
    const int csw = (lr & 7) << 4;
    const int rdk0 = lr * 128 + ((hi * 16) ^ csw);        // kk=0
    const int rdk1 = lr * 128 + ((64 + hi * 16) ^ csw);   // kk=1
    const int aBaseB = wm * 16384;                                      // buf0 A (wm half)
    const int bBaseB = 32768 + (wn >> 1) * 16384 + (wn & 1) * 8192;     // buf0 B

    // staging: thread tid writes linear LDS bytes [tid*16 + region]; logical row
    // = region_row0 + (tid>>3), source col pre-inverse-swizzled by ((row&7)<<4).
    const int srow = tid >> 3;                                   // 0..63
    const int scol = ((tid & 7) ^ ((tid >> 3) & 7)) * 8;         // elements, [0,64)
    const int so0 = srow * KM + scol;
    const int so1 = (64 + srow) * KM + scol;
    const u16* Am0 = A + (size_t)m0 * KM;
    const u16* Am1 = A + (size_t)(m0 + 128) * KM;
    const u16* Bm0 = B + (size_t)n0 * KM;
    const u16* Bm1 = B + (size_t)(n0 + 128) * KM;
    u16* ldst = lds + tid * 8;                                   // element base for DMA dest

    // B half-tile stage (rows r0..r0+127): 2 loads
    auto stageB = [&](const u16* src, int t, int regionEl) {
        __builtin_amdgcn_global_load_lds(AS1(src + so0 + t * 64), AS3(ldst + regionEl), 16, 0, 0);
        __builtin_amdgcn_global_load_lds(AS1(src + so1 + t * 64), AS3(ldst + regionEl + 4096), 16, 0, 0);
    };
    // A quarter-pair stage: which=0 -> {q0: rows 0-63, q2: rows 128-191};
    //                       which=1 -> {q1: rows 64-127, q3: rows 192-255}. 2 loads.
    auto stageA = [&](int t, int bufEl, int which) {
        const size_t ro = (size_t)(which * 64) * KM;
        __builtin_amdgcn_global_load_lds(AS1(Am0 + ro + so0 + t * 64),
                                         AS3(ldst + bufEl + which * 4096), 16, 0, 0);
        __builtin_amdgcn_global_load_lds(AS1(Am1 + ro + so0 + t * 64),
                                         AS3(ldst + bufEl + 8192 + which * 4096), 16, 0, 0);
    };

    f32x4 acc[8][4] = {};

    // prologue: B(0)h0, B(0)h1, A(0)w0, A(0)w1, B(1)h0, B(1)h1  (12 loads)
    stageB(Bm0, 0, 16384);
    stageB(Bm1, 0, 24576);
    stageA(0, 0, 0);
    stageA(0, 0, 1);
    stageB(Bm0, 1, 32768 + 16384);
    stageB(Bm1, 1, 32768 + 24576);
    VM_(6);                      // B(0) full + A(0){q0,q2} complete
    __builtin_amdgcn_s_barrier();

    #pragma unroll 1
    for (int i = 0; i < 33; ++i) {
        const int t = i * 2;
        const bool nl = (i < 32);
        short8 af[2][2];
        short8 bf[4][2];
        // -------- K-tile t (buf0) --------
        LDB_(0); LDA_(0, 0);
        stageA(t + 1, 32768, 0);
        MFMA_(0); ENDPH_();
        LDA_(0, 1);
        stageA(t + 1, 32768, 1);
        MFMA_(1); VM_(8); ENDPH_();                  // A(t){q1,q3} complete
        LDA_(0, 2);
        if (nl) stageB(Bm0, t + 2, 16384);
        MFMA_(2); ENDPH_();
        LDA_(0, 3);
        if (nl) stageB(Bm1, t + 2, 24576);
        MFMA_(3);
        if (nl) { VM_(6); } else { VM_(2); }         // B(t+1) + A(t+1){q0,q2}
        ENDPH_();
        // -------- K-tile t+1 (buf1) --------
        LDB_(65536); LDA_(65536, 0);
        if (nl) stageA(t + 2, 0, 0);
        MFMA_(0); ENDPH_();
        LDA_(65536, 1);
        if (nl) stageA(t + 2, 0, 1);
        MFMA_(1);
        if (nl) { VM_(8); } else { VM_(0); }         // A(t+1){q1,q3}
        ENDPH_();
        LDA_(65536, 2);
        if (nl) stageB(Bm0, t + 3, 32768 + 16384);
        MFMA_(2); ENDPH_();
        LDA_(65536, 3);
        if (nl) stageB(Bm1, t + 3, 32768 + 24576);
        MFMA_(3);
        if (nl) { VM_(6); }                          // B(t+2) + A(t+2){q0,q2}
        ENDPH_();
    }

    // epilogue: C[row][col] = acc + bias, C/D layout col=lane&15, row=(lane>>4)*4+r
    const int colb = n0 + wn * 64 + lr;
    const int rowb = m0 + wm * 128 + hi * 4;
    #pragma unroll
    for (int nj = 0; nj < 4; ++nj) {
        const int col = colb + nj * 16;
        const float bv = bias[col];
        #pragma unroll
        for (int mi = 0; mi < 8; ++mi) {
            float* Cp = C + (size_t)(rowb + mi * 16) * NOUT + col;
            #pragma unroll
            for (int r = 0; r < 4; ++r)
                Cp[(size_t)r * NOUT] = acc[mi][nj][r] + bv;
        }
    }
}

extern "C" void kernel_launch(void* const* d_in, const int* in_sizes, int n_in,
                              void* d_out, int out_size, void* d_ws, size_t ws_size,
                              hipStream_t stream) {
    const float* x  = (const float*)d_in[0];   // [4,2048,4096]
    const float* Wb = (const float*)d_in[1];   // [4096,4096]
    const float* bb = (const float*)d_in[2];   // [4096]
    const float* lA = (const float*)d_in[3];   // [8,8,4096]
    const float* lB = (const float*)d_in[4];   // [8,4096,8]
    const float* rW = (const float*)d_in[5];   // [8,4096]
    const float* rb = (const float*)d_in[6];   // [8]
    float* out = (float*)d_out;                // [4,2048,4096] fp32

    char* ws = (char*)d_ws;
    float* logits = (float*)ws;                            // 32 fp32
    u16* Abf      = (u16*)(ws + 256);                      // 64*4096 bf16 = 512 KiB
    u16* Xext     = (u16*)(ws + 524800);                   // 8192*4224 bf16 = 69.2 MB
    u16* Wext     = (u16*)(ws + 524800 + 69206016ULL);     // 4096*4224 bf16 = 34.6 MB
    // colpart [1024][4096] fp32 = 16 MB overlaid on Wext[0..16MB); colsum [4][4096]
    // fp32 = 64 KiB overlaid at Wext+20MB. Both fully consumed (k_red/k_lgt) BEFORE
    // k_prep2 writes Wext (stream-ordered).
    float* colpart = (float*)Wext;
    float* colsum  = (float*)((char*)Wext + (20u << 20));

    k_prep1 <<<2048, 256, 0, stream>>>(x, Xext, colpart, lA, Abf);   // convx || abf
    k_red   <<<64,   256, 0, stream>>>(colpart, colsum);             // colpart -> colsum
    k_lgt   <<<32,   256, 0, stream>>>(colsum, rW, logits);          // raw router logits
    k_prep2 <<<9472, 256, 0, stream>>>(Xext, Abf, logits, rb, Xext,  // hgemm || conv8 || wlora
                                       Wb, Wext, lB);
    k_main  <<<512,  512, 0, stream>>>(Xext, Wext, bb, out);         // 256^2 8-phase GEMM + bias
}

// Round 5
// 542.890 us; speedup vs baseline: 1.0529x; 1.0408x over previous
//
#include <hip/hip_runtime.h>
#include <hip/hip_bf16.h>

// MOELoraLinear: out = x@W_base^T + b_base + SCALING * router-weighted LoRA.
// LoRA-up folded into main GEMM via K-extension: Xext[8192,4224]=[bf16(x)|hw'|0pad],
// Wext[4096,4224]=[bf16(W_base)|lora_B|0pad]; one bf16 MFMA GEMM K=4224 + bias.
// R7: launch graph reverted to R2's separate kernels (552us best; R4 fusion +13us).
//     k_main phases re-partitioned (mi-half, k): per-phase LDS reads 8/4/8/4 (was
//     12/4/4/4), 16 independent MFMAs per phase, compiler-managed lgkmcnt (no forced
//     lgkmcnt(0)), per-tile staging {PhA: B(t+1), PhB: A(t+1)} with vmcnt(4)/vmcnt(2).

typedef unsigned short u16;
typedef __attribute__((ext_vector_type(8))) short short8;       // 8 bf16 (MFMA A/B frag)
typedef __attribute__((ext_vector_type(8))) unsigned short u16x8;
typedef __attribute__((ext_vector_type(4))) float f32x4;        // MFMA C/D frag

#define AS1(p) ((const __attribute__((address_space(1))) void*)(p))
#define AS3(p) ((__attribute__((address_space(3))) void*)(p))

constexpr int KM   = 4224;   // extended+padded K (66 * 64), row stride of Xext/Wext
constexpr int NOUT = 4096;

__device__ __forceinline__ u16 f2bf(float f) {
    union { float f; unsigned int u; } v; v.f = f;
    unsigned int r = v.u + 0x7fffu + ((v.u >> 16) & 1u);   // RNE
    return (u16)(r >> 16);
}

// ---- fused: x fp32 -> bf16 into Xext[:, :4096]  +  per-block column sums ----
// grid 512: b = blk>>7, sc = blk&127 -> rows [b*2048 + sc*16, +16)
__global__ __launch_bounds__(256) void k_convx(const float* __restrict__ x,
                                               u16* __restrict__ Xext,
                                               float* __restrict__ colpart) {
    const int t = threadIdx.x;
    const int row0 = (blockIdx.x >> 7) * 2048 + (blockIdx.x & 127) * 16;
    float4 cs[4] = {{0,0,0,0},{0,0,0,0},{0,0,0,0},{0,0,0,0}};   // [g*2+h]
    for (int r = 0; r < 16; ++r) {
        size_t roff = (size_t)(row0 + r) * 4096;
        #pragma unroll
        for (int g = 0; g < 2; ++g) {
            int col = g * 2048 + t * 8;
            const float4* p = (const float4*)(x + roff + col);
            float4 v0 = p[0], v1 = p[1];
            cs[2*g].x += v0.x; cs[2*g].y += v0.y; cs[2*g].z += v0.z; cs[2*g].w += v0.w;
            cs[2*g+1].x += v1.x; cs[2*g+1].y += v1.y; cs[2*g+1].z += v1.z; cs[2*g+1].w += v1.w;
            u16x8 o;
            o[0]=f2bf(v0.x); o[1]=f2bf(v0.y); o[2]=f2bf(v0.z); o[3]=f2bf(v0.w);
            o[4]=f2bf(v1.x); o[5]=f2bf(v1.y); o[6]=f2bf(v1.z); o[7]=f2bf(v1.w);
            *(u16x8*)(Xext + (size_t)(row0 + r) * KM + col) = o;
        }
    }
    float* cp = colpart + (size_t)blockIdx.x * 4096;
    #pragma unroll
    for (int g = 0; g < 2; ++g) {
        *(float4*)(cp + g * 2048 + t * 8)     = cs[2*g];
        *(float4*)(cp + g * 2048 + t * 8 + 4) = cs[2*g+1];
    }
}

// ---- colsum[b][c] = sum_sc colpart[b*128+sc][c]; grid 64 = b*16+chunk ----
__global__ __launch_bounds__(256) void k_red(const float* __restrict__ colpart,
                                             float* __restrict__ colsum) {
    const int b = blockIdx.x >> 4;
    const int col = (blockIdx.x & 15) * 256 + threadIdx.x;
    const float* p = colpart + (size_t)b * 128 * 4096 + col;
    float acc = 0.f;
    #pragma unroll 8
    for (int sc = 0; sc < 128; ++sc) acc += p[(size_t)sc * 4096];
    colsum[b * 4096 + col] = acc;
}

// ---- logits_raw[b,e] = sum_col colsum[b,col] * rW[e,col]  (grid 32 = b*8+e) ----
__global__ __launch_bounds__(256) void k_lgt(const float* __restrict__ colsum,
                                             const float* __restrict__ rW,
                                             float* __restrict__ logits) {
    const int b = blockIdx.x >> 3, e = blockIdx.x & 7;
    const int t = threadIdx.x;
    const float4* cp = (const float4*)(colsum + b * 4096 + t * 16);
    const float4* wp = (const float4*)(rW + e * 4096 + t * 16);
    float acc = 0.f;
    #pragma unroll
    for (int j = 0; j < 4; ++j) {
        float4 c = cp[j], w = wp[j];
        acc += c.x * w.x + c.y * w.y + c.z * w.z + c.w * w.w;
    }
    __shared__ float red[256];
    red[t] = acc;
    __syncthreads();
    for (int off = 128; off > 0; off >>= 1) {
        if (t < off) red[t] += red[t + off];
        __syncthreads();
    }
    if (t == 0) logits[b * 8 + e] = red[0];
}

// ---- W_base fp32 [4096][4096] -> bf16 into Wext[:, :4096] ----
__global__ void k_conv8(const float* __restrict__ src, u16* __restrict__ dst) {
    size_t t = (size_t)blockIdx.x * 256 + threadIdx.x;
    size_t base = t * 8;
    size_t row = base >> 12;
    int col = (int)(base & 4095);
    const float4* s = (const float4*)(src + base);
    float4 v0 = s[0], v1 = s[1];
    u16x8 o;
    o[0]=f2bf(v0.x); o[1]=f2bf(v0.y); o[2]=f2bf(v0.z); o[3]=f2bf(v0.w);
    o[4]=f2bf(v1.x); o[5]=f2bf(v1.y); o[6]=f2bf(v1.z); o[7]=f2bf(v1.w);
    *(u16x8*)(dst + row * KM + col) = o;
}

// ---- lora_B [E,O,R] fp32 -> Wext[o][4096 + e*8 + r]; also zero K-pad [4160,4224) ----
__global__ void k_wlora(const float* __restrict__ lb, u16* __restrict__ Wext) {
    int f = blockIdx.x * 256 + threadIdx.x;
    int e = f >> 15, o = (f >> 3) & 4095, r = f & 7;
    Wext[(size_t)o * KM + 4096 + e * 8 + r] = f2bf(lb[f]);
    // pad zero: f in [0, 262144) == 4096 rows x 64 pad cols
    Wext[(size_t)(f >> 6) * KM + 4160 + (f & 63)] = 0;
}

// ---- lora_A [E,R,D] fp32 -> Abf [64][4096] bf16 ----
__global__ void k_abf(const float* __restrict__ la, u16* __restrict__ Abf) {
    int f = blockIdx.x * 256 + threadIdx.x;
    Abf[f] = f2bf(la[f]);
}

// ---- h-GEMM: Xext[:, 4096+er] = f2bf( (Xbf @ Abf^T)[m,er] * SCALING*softmax(...)[b(m),e] )
// grid 256 blocks x 256 thr (4 waves). M-tile 32. Each wave owns K-chunk of 1024,
// private double-buffered LDS, no in-loop barriers; cross-wave LDS reduce at end.
// Also zero-fills the K-pad columns [4160,4224) of its 32 rows.
__global__ __launch_bounds__(256) void k_hgemm(const u16* __restrict__ Xb,
                                               const u16* __restrict__ Ab,
                                               const float* __restrict__ logits,
                                               const float* __restrict__ rb,
                                               u16* __restrict__ Hout) {
    __shared__ u16 As[8 * 1024];     // [wave*2+buf][32*32]
    __shared__ u16 Bs[8 * 2048];     // [wave*2+buf][64*32]
    __shared__ float Red[4 * 2048];  // [wave][32*64]
    __shared__ float wscL[8];
    const int tid = threadIdx.x, lane = tid & 63, w = tid >> 6;
    const int m0 = blockIdx.x * 32;
    const int b = blockIdx.x >> 6;      // batch (2048 rows = 64 blocks per batch)

    if (tid < 8) {
        float l[8], mx = -1e30f;
        #pragma unroll
        for (int j = 0; j < 8; ++j) {
            l[j] = logits[b * 8 + j] * (1.0f / 2048.0f) + rb[j];
            mx = fmaxf(mx, l[j]);
        }
        float s = 0.f;
        #pragma unroll
        for (int j = 0; j < 8; ++j) s += expf(l[j] - mx);
        wscL[tid] = 2.0f * expf(l[tid] - mx) / s;   // SCALING = 2.0
    }
    // drain the logits/rb loads so they don't pollute vmcnt bookkeeping below
    asm volatile("s_waitcnt vmcnt(0)" ::: "memory");

    f32x4 acc[2][4] = {};
    const int kbase = w * 1024;

    auto issue = [&](int it, int buf) {
        const int kt = kbase + it * 32;
        u16* Aw = As + (w * 2 + buf) * 1024;
        u16* Bw = Bs + (w * 2 + buf) * 2048;
        #pragma unroll
        for (int i = 0; i < 2; ++i) {
            int f = lane + i * 64;
            __builtin_amdgcn_global_load_lds(
                AS1(Xb + (size_t)(m0 + (f >> 2)) * KM + kt + (f & 3) * 8),
                AS3(Aw + f * 8), 16, 0, 0);
        }
        #pragma unroll
        for (int i = 0; i < 4; ++i) {
            int f = lane + i * 64;
            __builtin_amdgcn_global_load_lds(
                AS1(Ab + (size_t)(f >> 2) * 4096 + kt + (f & 3) * 8),
                AS3(Bw + f * 8), 16, 0, 0);
        }
    };

    issue(0, 0);
    for (int it = 0; it < 32; ++it) {
        const int buf = it & 1;
        if (it + 1 < 32) {
            issue(it + 1, buf ^ 1);
            asm volatile("s_waitcnt vmcnt(6)" ::: "memory");   // drain the 6 older (this iter's) DMAs
        } else {
            asm volatile("s_waitcnt vmcnt(0)" ::: "memory");
        }
        const u16* Aw = As + (w * 2 + buf) * 1024;
        const u16* Bw = Bs + (w * 2 + buf) * 2048;
        short8 af[2], bfr[4];
        #pragma unroll
        for (int mi = 0; mi < 2; ++mi)
            af[mi] = *(const short8*)(Aw + (mi * 16 + (lane & 15)) * 32 + (lane >> 4) * 8);
        #pragma unroll
        for (int nj = 0; nj < 4; ++nj)
            bfr[nj] = *(const short8*)(Bw + (nj * 16 + (lane & 15)) * 32 + (lane >> 4) * 8);
        #pragma unroll
        for (int mi = 0; mi < 2; ++mi)
            #pragma unroll
            for (int nj = 0; nj < 4; ++nj)
                acc[mi][nj] = __builtin_amdgcn_mfma_f32_16x16x32_bf16(af[mi], bfr[nj], acc[mi][nj], 0, 0, 0);
        asm volatile("" ::: "memory");
    }

    const int quad = lane >> 4, lcol = lane & 15;
    #pragma unroll
    for (int mi = 0; mi < 2; ++mi)
        #pragma unroll
        for (int nj = 0; nj < 4; ++nj)
            #pragma unroll
            for (int r = 0; r < 4; ++r)
                Red[w * 2048 + (mi * 16 + quad * 4 + r) * 64 + nj * 16 + lcol] = acc[mi][nj][r];
    __syncthreads();

    const int o = tid * 8, row = o >> 6, col = o & 63;
    float s0=0,s1=0,s2=0,s3=0,s4=0,s5=0,s6=0,s7=0;
    #pragma unroll
    for (int ww = 0; ww < 4; ++ww) {
        const float4* p = (const float4*)(Red + ww * 2048 + o);
        float4 v0 = p[0], v1 = p[1];
        s0+=v0.x; s1+=v0.y; s2+=v0.z; s3+=v0.w;
        s4+=v1.x; s5+=v1.y; s6+=v1.z; s7+=v1.w;
    }
    const float wgt = wscL[col >> 3];
    u16x8 out;
    out[0]=f2bf(s0*wgt); out[1]=f2bf(s1*wgt); out[2]=f2bf(s2*wgt); out[3]=f2bf(s3*wgt);
    out[4]=f2bf(s4*wgt); out[5]=f2bf(s5*wgt); out[6]=f2bf(s6*wgt); out[7]=f2bf(s7*wgt);
    *(u16x8*)(Hout + (size_t)(m0 + row) * KM + 4096 + col) = out;
    // zero K-pad: 32 rows x 64 cols per block
    u16x8 zz = {0,0,0,0,0,0,0,0};
    *(u16x8*)(Hout + (size_t)(m0 + (tid >> 3)) * KM + 4160 + (tid & 7) * 8) = zz;
}

// ================= main GEMM: 256x256 tile, BK=64, (mi-half,k)-phased =================
// C[8192,4096] = Xext @ Wext^T + bias. K = 4224 = 66 tiles of 64, 1 tile per 4 phases.
// LDS (bytes): buf b in {0,1}: A @ b*65536 (rows linear, 128B/row); B @ b*65536+32768.
// Swizzle: logical (row, colbyte) stored at colbyte ^ ((row&7)<<4) within each 128B row.
// Phases per tile: PhA: {B k0 (4 ds) + A mi0-3 k0 (4 ds)} MFMA mi0-3,k0 (16 indep)
//                  PhB: {A mi4-7 k0 (4)}                  MFMA mi4-7,k0
//                  PhC: {B k1 (4) + A mi0-3 k1 (4)}       MFMA mi0-3,k1
//                  PhD: {A mi4-7 k1 (4)}                  MFMA mi4-7,k1
// Staging per tile: PhA: B(t+1) h0+h1 (4 loads); PhB: A(t+1) w0+w1 (4 loads).
// Waits: vmcnt(4) end-PhA (A-w1(t) before PhB reads); vmcnt(2) end-PhD (B(t+1)+A-w0(t+1)
// before next tile's reads; A-w1(t+1) stays in flight). Tail tile 65: 0 / skip.
// lgkmcnt: compiler-managed (C++ ds_reads -> fine-grained per-use waits).

#define LDBk_(bufB, rdk) do { \
    const char* bp_ = ldsc + bBaseB + (bufB); \
    _Pragma("unroll") \
    for (int nj_ = 0; nj_ < 4; ++nj_) \
        bf[nj_] = *(const short8*)(bp_ + nj_ * 2048 + (rdk)); \
} while (0)

#define LDAh_(bufB, h, rdk) do { \
    const char* ap_ = ldsc + aBaseB + (bufB) + (h) * 8192; \
    _Pragma("unroll") \
    for (int q_ = 0; q_ < 4; ++q_) \
        af[q_] = *(const short8*)(ap_ + q_ * 2048 + (rdk)); \
} while (0)

// 16 fully-independent MFMAs (4 mi x 4 nj, single k-step)
#define MFMAh_(h) do { \
    __builtin_amdgcn_s_barrier(); \
    __builtin_amdgcn_s_setprio(1); \
    _Pragma("unroll") \
    for (int q_ = 0; q_ < 4; ++q_) \
        _Pragma("unroll") \
        for (int nj_ = 0; nj_ < 4; ++nj_) \
            acc[(h)*4+q_][nj_] = __builtin_amdgcn_mfma_f32_16x16x32_bf16(af[q_], bf[nj_], acc[(h)*4+q_][nj_], 0, 0, 0); \
    __builtin_amdgcn_s_setprio(0); \
} while (0)

#define ENDPH_() __builtin_amdgcn_s_barrier()
#define VM_(n)   asm volatile("s_waitcnt vmcnt(" #n ")" ::: "memory")

__global__ __launch_bounds__(512, 2) void k_main(const u16* __restrict__ A, const u16* __restrict__ B,
                                                 const float* __restrict__ bias, float* __restrict__ C) {
    __shared__ __align__(16) u16 lds[65536];   // 128 KiB
    const char* ldsc = (const char*)lds;
    const int tid = threadIdx.x;
    const int lane = tid & 63;
    const int w = tid >> 6;
    const int wm = w >> 2;        // 0..1  (M half)
    const int wn = w & 3;         // 0..3  (N quarter)
    const int lr = lane & 15, hi = lane >> 4;

    // bijective XCD swizzle: 512 blocks, 64/XCD; tiles 32(M) x 16(N), N fast (A-panel L2 reuse)
    const int bid = blockIdx.x;
    const int swz = (bid & 7) * 64 + (bid >> 3);
    const int m0 = (swz >> 4) * 256;
    const int n0 = (swz & 15) * 256;

    // ds_read byte offsets within a region (swizzled; XOR depends only on lane)
    const int csw = (lr & 7) << 4;
    const int rdk0 = lr * 128 + ((hi * 16) ^ csw);        // k-step 0
    const int rdk1 = lr * 128 + ((64 + hi * 16) ^ csw);   // k-step 1
    const int aBaseB = wm * 16384;                                      // buf0 A (wm half)
    const int bBaseB = 32768 + (wn >> 1) * 16384 + (wn & 1) * 8192;     // buf0 B

    // staging: thread tid writes linear LDS bytes [tid*16 + region]; logical row
    // = region_row0 + (tid>>3), source col pre-inverse-swizzled by ((row&7)<<4).
    const int srow = tid >> 3;                                   // 0..63
    const int scol = ((tid & 7) ^ ((tid >> 3) & 7)) * 8;         // elements, [0,64)
    const int so0 = srow * KM + scol;
    const int so1 = (64 + srow) * KM + scol;
    const u16* Am0 = A + (size_t)m0 * KM;
    const u16* Am1 = A + (size_t)(m0 + 128) * KM;
    const u16* Bm0 = B + (size_t)n0 * KM;
    const u16* Bm1 = B + (size_t)(n0 + 128) * KM;
    u16* ldst = lds + tid * 8;                                   // element base for DMA dest

    // B half-tile stage (128 rows): 2 loads
    auto stageB = [&](const u16* src, int t, int regionEl) {
        __builtin_amdgcn_global_load_lds(AS1(src + so0 + t * 64), AS3(ldst + regionEl), 16, 0, 0);
        __builtin_amdgcn_global_load_lds(AS1(src + so1 + t * 64), AS3(ldst + regionEl + 4096), 16, 0, 0);
    };
    // A quarter-pair stage: which=0 -> {rows 0-63, 128-191} (mi0-3 of both halves);
    //                       which=1 -> {rows 64-127, 192-255} (mi4-7). 2 loads.
    auto stageA = [&](int t, int bufEl, int which) {
        const size_t ro = (size_t)(which * 64) * KM;
        __builtin_amdgcn_global_load_lds(AS1(Am0 + ro + so0 + t * 64),
                                         AS3(ldst + bufEl + which * 4096), 16, 0, 0);
        __builtin_amdgcn_global_load_lds(AS1(Am1 + ro + so0 + t * 64),
                                         AS3(ldst + bufEl + 8192 + which * 4096), 16, 0, 0);
    };

    f32x4 acc[8][4] = {};

    // prologue = tile(-1)'s staging of tile 0, same issue order as steady state:
    // {B(0)h0, B(0)h1, A(0)w0, A(0)w1} then vmcnt(2) (A-w1 may stay in flight)
    stageB(Bm0, 0, 16384);
    stageB(Bm1, 0, 24576);
    stageA(0, 0, 0);
    stageA(0, 0, 1);
    VM_(2);
    __builtin_amdgcn_s_barrier();

    short8 af[4];
    short8 bf[4];

    #pragma unroll 1
    for (int i = 0; i < 33; ++i) {
        const int t = i * 2;
        const bool nl = (i < 32);
        // ======== tile t (read buf0, stage tile t+1 into buf1) ========
        // PhA
        LDBk_(0, rdk0); LDAh_(0, 0, rdk0);
        stageB(Bm0, t + 1, 32768 + 16384);
        stageB(Bm1, t + 1, 32768 + 24576);
        MFMAh_(0);
        VM_(4); ENDPH_();                      // A-w1(t) ready for PhB reads
        // PhB
        LDAh_(0, 1, rdk0);
        stageA(t + 1, 32768, 0);
        stageA(t + 1, 32768, 1);
        MFMAh_(1); ENDPH_();
        // PhC
        LDBk_(0, rdk1); LDAh_(0, 0, rdk1);
        MFMAh_(0); ENDPH_();
        // PhD
        LDAh_(0, 1, rdk1);
        MFMAh_(1);
        VM_(2); ENDPH_();                      // B(t+1)+A-w0(t+1) ready for next tile
        // ======== tile t+1 (read buf1, stage tile t+2 into buf0) ========
        // PhA
        LDBk_(65536, rdk0); LDAh_(65536, 0, rdk0);
        if (nl) { stageB(Bm0, t + 2, 16384); stageB(Bm1, t + 2, 24576); }
        MFMAh_(0);
        if (nl) { VM_(4); } else { VM_(0); }   // A-w1(t+1) ready
        ENDPH_();
        // PhB
        LDAh_(65536, 1, rdk0);
        if (nl) { stageA(t + 2, 0, 0); stageA(t + 2, 0, 1); }
        MFMAh_(1); ENDPH_();
        // PhC
        LDBk_(65536, rdk1); LDAh_(65536, 0, rdk1);
        MFMAh_(0); ENDPH_();
        // PhD
        LDAh_(65536, 1, rdk1);
        MFMAh_(1);
        if (nl) { VM_(2); }
        ENDPH_();
    }

    // epilogue: C[row][col] = acc + bias, C/D layout col=lane&15, row=(lane>>4)*4+r
    const int colb = n0 + wn * 64 + lr;
    const int rowb = m0 + wm * 128 + hi * 4;
    #pragma unroll
    for (int nj = 0; nj < 4; ++nj) {
        const int col = colb + nj * 16;
        const float bv = bias[col];
        #pragma unroll
        for (int mi = 0; mi < 8; ++mi) {
            float* Cp = C + (size_t)(rowb + mi * 16) * NOUT + col;
            #pragma unroll
            for (int r = 0; r < 4; ++r)
                Cp[(size_t)r * NOUT] = acc[mi][nj][r] + bv;
        }
    }
}

extern "C" void kernel_launch(void* const* d_in, const int* in_sizes, int n_in,
                              void* d_out, int out_size, void* d_ws, size_t ws_size,
                              hipStream_t stream) {
    const float* x  = (const float*)d_in[0];   // [4,2048,4096]
    const float* Wb = (const float*)d_in[1];   // [4096,4096]
    const float* bb = (const float*)d_in[2];   // [4096]
    const float* lA = (const float*)d_in[3];   // [8,8,4096]
    const float* lB = (const float*)d_in[4];   // [8,4096,8]
    const float* rW = (const float*)d_in[5];   // [8,4096]
    const float* rb = (const float*)d_in[6];   // [8]
    float* out = (float*)d_out;                // [4,2048,4096] fp32

    char* ws = (char*)d_ws;
    float* logits = (float*)ws;                            // 32 fp32
    u16* Abf      = (u16*)(ws + 256);                      // 64*4096 bf16 = 512 KiB
    u16* Xext     = (u16*)(ws + 524800);                   // 8192*4224 bf16 = 69.2 MB
    u16* Wext     = (u16*)(ws + 524800 + 69206016ULL);     // 4096*4224 bf16 = 34.6 MB
    // colpart [512][4096] fp32 = 8 MB overlaid on Wext[0..8MB); colsum [4][4096] fp32
    // = 64 KiB overlaid at Wext+16MB. Both fully consumed (k_red/k_lgt) BEFORE
    // k_conv8/k_wlora write Wext (stream-ordered).
    float* colpart = (float*)Wext;
    float* colsum  = (float*)((char*)Wext + (16u << 20));

    k_abf   <<<1024, 256, 0, stream>>>(lA, Abf);             // lora_A -> bf16
    k_convx <<<512,  256, 0, stream>>>(x, Xext, colpart);    // x -> bf16 + column sums
    k_red   <<<64,   256, 0, stream>>>(colpart, colsum);     // colpart -> per-batch colsum
    k_lgt   <<<32,   256, 0, stream>>>(colsum, rW, logits);  // raw router logits
    k_hgemm <<<256,  256, 0, stream>>>(Xext, Abf, logits, rb, Xext); // hw' -> Xext[:,4096:4160] + pad0
    k_conv8 <<<8192, 256, 0, stream>>>(Wb, Wext);            // W_base -> Wext[:, :4096]
    k_wlora <<<1024, 256, 0, stream>>>(lB, Wext);            // lora_B -> Wext[:, 4096:4160] + pad0
    k_main  <<<512,  512, 0, stream>>>(Xext, Wext, bb, out); // 256^2 GEMM + bias
}